// Round 8
// baseline (1192.910 us; speedup 1.0000x reference)
//
#include <hip/hip_runtime.h>
#include <hip/hip_bf16.h>

// ---------- types ----------
typedef __attribute__((ext_vector_type(8))) short bfx8;   // 8 bf16 in 4 VGPRs
typedef __attribute__((ext_vector_type(4))) float fx4;    // MFMA accumulator

__device__ __forceinline__ short f2bf(float f) {
    union { float f; unsigned u; } v; v.f = f;
    unsigned r = v.u + 0x7fffu + ((v.u >> 16) & 1u);      // RNE
    return (short)(r >> 16);
}
__device__ __forceinline__ float bf2f(short b) {
    union { unsigned u; float f; } v; v.u = ((unsigned)(unsigned short)b) << 16; return v.f;
}

// ==========================================================================
// Kernel 1: projection GEMM with f32->bf16 hi/lo split (3-term MFMA).
// ==========================================================================
__global__ __launch_bounds__(256) void proj_kernel(
    const float* __restrict__ X, const float* __restrict__ Y,
    const float* __restrict__ wq, const float* __restrict__ wkv,
    short* __restrict__ QpX, short* __restrict__ KpX, short* __restrict__ VbX,
    short* __restrict__ QpY, short* __restrict__ KpY, short* __restrict__ VbY)
{
    const int inp = blockIdx.z;
    const float* A = inp ? Y : X;
    short* Qp = inp ? QpY : QpX;
    short* Kp = inp ? KpY : KpX;
    short* Vb = inp ? VbY : VbX;
    const int mb = blockIdx.x;          // 0..63  (M tiles of 128)
    const int nb = blockIdx.y;          // 0..11  (N tiles of 128)
    const int tid = threadIdx.x;
    const int lane = tid & 63;
    const int w = tid >> 6, wm = w >> 1, wn = w & 1;
    const int l15 = lane & 15, g8 = (lane >> 4) * 8;

    __shared__ short As[128][72];   // [row][k_hi 0..31 | k_lo 32..63 | pad]
    __shared__ short Bs[128][72];   // [col][k_hi | k_lo | pad]  (W transposed)

    const float* Bsrc; int ldb, nbase0;
    if (nb < 4) { Bsrc = wq;  ldb = 512;  nbase0 = nb * 128; }
    else        { Bsrc = wkv; ldb = 1024; nbase0 = nb * 128 - 512; }

    fx4 acc[4][4];
    const fx4 z4 = {0.f, 0.f, 0.f, 0.f};
    for (int i = 0; i < 4; i++) for (int j = 0; j < 4; j++) acc[i][j] = z4;

    const int arow = tid >> 1, ahalf = (tid & 1) * 16;
    const int bk = tid >> 3, bnseg = (tid & 7) * 16;

    for (int kb = 0; kb < 512; kb += 32) {
        __syncthreads();
        { // stage A (hi/lo split)
            const float* src = A + (size_t)(mb * 128 + arow) * 512 + kb + ahalf;
            bfx8 h0, h1, l0, l1;
            #pragma unroll
            for (int q = 0; q < 4; q++) {
                float4 v = *(const float4*)(src + q * 4);
                float vv[4] = {v.x, v.y, v.z, v.w};
                #pragma unroll
                for (int c = 0; c < 4; c++) {
                    int idx = q * 4 + c;
                    short h = f2bf(vv[c]);
                    short l = f2bf(vv[c] - bf2f(h));
                    if (idx < 8) { h0[idx] = h; l0[idx] = l; }
                    else         { h1[idx - 8] = h; l1[idx - 8] = l; }
                }
            }
            *(bfx8*)&As[arow][ahalf] = h0;      *(bfx8*)&As[arow][ahalf + 8] = h1;
            *(bfx8*)&As[arow][32 + ahalf] = l0; *(bfx8*)&As[arow][32 + ahalf + 8] = l1;
        }
        { // stage B transposed (hi/lo split)
            const float* src = Bsrc + (size_t)(kb + bk) * ldb + nbase0 + bnseg;
            #pragma unroll
            for (int q = 0; q < 4; q++) {
                float4 v = *(const float4*)(src + q * 4);
                float vv[4] = {v.x, v.y, v.z, v.w};
                #pragma unroll
                for (int c = 0; c < 4; c++) {
                    int n = bnseg + q * 4 + c;
                    short h = f2bf(vv[c]);
                    Bs[n][bk] = h;
                    Bs[n][32 + bk] = f2bf(vv[c] - bf2f(h));
                }
            }
        }
        __syncthreads();
        bfx8 ah[4], al[4], bh[4], bl[4];
        #pragma unroll
        for (int mt = 0; mt < 4; mt++) {
            int r = wm * 64 + mt * 16 + l15;
            ah[mt] = *(bfx8*)&As[r][g8];
            al[mt] = *(bfx8*)&As[r][32 + g8];
        }
        #pragma unroll
        for (int nt = 0; nt < 4; nt++) {
            int r = wn * 64 + nt * 16 + l15;
            bh[nt] = *(bfx8*)&Bs[r][g8];
            bl[nt] = *(bfx8*)&Bs[r][32 + g8];
        }
        #pragma unroll
        for (int mt = 0; mt < 4; mt++)
            #pragma unroll
            for (int nt = 0; nt < 4; nt++) {
                acc[mt][nt] = __builtin_amdgcn_mfma_f32_16x16x32_bf16(ah[mt], bh[nt], acc[mt][nt], 0, 0, 0);
                acc[mt][nt] = __builtin_amdgcn_mfma_f32_16x16x32_bf16(ah[mt], bl[nt], acc[mt][nt], 0, 0, 0);
                acc[mt][nt] = __builtin_amdgcn_mfma_f32_16x16x32_bf16(al[mt], bh[nt], acc[mt][nt], 0, 0, 0);
            }
    }
    // epilogue: scatter to packed buffers
    #pragma unroll
    for (int mt = 0; mt < 4; mt++)
        #pragma unroll
        for (int nt = 0; nt < 4; nt++)
            #pragma unroll
            for (int r = 0; r < 4; r++) {
                int row = mb * 128 + wm * 64 + mt * 16 + (lane >> 4) * 4 + r;
                int col = nb * 128 + wn * 64 + nt * 16 + l15;
                float v = acc[mt][nt][r];
                int b = row >> 10, n = row & 1023;
                if (col < 512) {
                    v *= 0.125f;   // SCALE folded into Q (exact pow2)
                    int h = col >> 6, d = col & 63;
                    size_t base = ((size_t)(b * 8 + h) * 1024 + n) * 128;
                    short hi = f2bf(v);
                    Qp[base + d] = hi;
                    Qp[base + 64 + d] = f2bf(v - bf2f(hi));
                } else if (col < 1024) {
                    int cc = col - 512;
                    int h = cc >> 6, d = cc & 63;
                    size_t base = ((size_t)(b * 8 + h) * 1024 + n) * 128;
                    short hi = f2bf(v);
                    Kp[base + d] = hi;
                    Kp[base + 64 + d] = f2bf(v - bf2f(hi));
                } else {
                    Vb[(size_t)row * 512 + (col - 1024)] = f2bf(v);
                }
            }
}

// ==========================================================================
// Kernel 2: transpose V: Vb [8192][512] bf16 -> Vt [b*8+h][64][1024] bf16
// ==========================================================================
__global__ __launch_bounds__(256) void transv_kernel(
    const short* __restrict__ VbX, const short* __restrict__ VbY,
    short* __restrict__ VtX, short* __restrict__ VtY)
{
    const int inp = blockIdx.z;
    const short* Vb = inp ? VbY : VbX;
    short* Vt = inp ? VtY : VtX;
    const int bh = blockIdx.y, b = bh >> 3, h = bh & 7;
    const int nt = blockIdx.x;           // 0..15 (n tiles of 64)
    const int tid = threadIdx.x;
    __shared__ short tile[64][66];
    {
        int r = tid >> 2, c0 = (tid & 3) * 16;
        const short* src = Vb + ((size_t)(b * 1024 + nt * 64 + r)) * 512 + h * 64 + c0;
        bfx8 v0 = *(const bfx8*)src;
        bfx8 v1 = *(const bfx8*)(src + 8);
        #pragma unroll
        for (int i = 0; i < 8; i++) { tile[r][c0 + i] = v0[i]; tile[r][c0 + 8 + i] = v1[i]; }
    }
    __syncthreads();
    {
        int d = tid >> 2, n0 = (tid & 3) * 16;
        bfx8 o0, o1;
        #pragma unroll
        for (int i = 0; i < 8; i++) { o0[i] = tile[n0 + i][d]; o1[i] = tile[n0 + 8 + i][d]; }
        short* dst = Vt + ((size_t)(bh * 64 + d)) * 1024 + nt * 64 + n0;
        *(bfx8*)dst = o0;
        *(bfx8*)(dst + 8) = o1;
    }
}

// ==========================================================================
// Kernel 3 (v4): fused attention per (dir, b*8+h, 16-row q block).
// v3 structure, occupancy-tuned: LDS trimmed to 40832B (psumPV overlays the
// dead hist/cand region) -> 4 blocks/CU; __launch_bounds__(512,8) caps
// VGPR <= 64 -> 8 waves/SIMD. Selection math identical to v3.
// ==========================================================================
#define PBUF_BYTES 32768              // 16 rows * 2048 B
#define HIST_OFF   32768              // 16*96*4 = 6144 (cand + psumPV alias here)
#define PMX_OFF    38912              // 16*8*4 = 512
#define PMN_OFF    39424              // 512
#define PSUM_OFF   39936              // 512
#define RMX_OFF    40448              // 64
#define RMN_OFF    40512              // 64
#define RT_OFF     40576              // 64
#define RB_OFF     40640              // 64
#define RN_OFF     40704              // 64
#define RC_OFF     40768              // 64
#define ATTN_LDS   40832

__global__ __launch_bounds__(512, 8) void attn_kernel(
    const short* __restrict__ QpX, const short* __restrict__ KpX, const short* __restrict__ VtX,
    const short* __restrict__ QpY, const short* __restrict__ KpY, const short* __restrict__ VtY,
    short* __restrict__ inner)
{
    extern __shared__ char smem[];
    unsigned* histU  = (unsigned*)(smem + HIST_OFF);   // [16][96]
    float*    candF  = (float*)(smem + HIST_OFF);      // [16][64] alias after hist dead
    float*    psumPV = (float*)(smem + HIST_OFF);      // [4][64][4] alias after cand dead
    float*    partmx = (float*)(smem + PMX_OFF);       // [16][8]
    float*    partmn = (float*)(smem + PMN_OFF);       // [16][8]
    float*    partsum= (float*)(smem + PSUM_OFF);      // [16][8]
    float*    rowMx  = (float*)(smem + RMX_OFF);       // [16]
    float*    rowMn  = (float*)(smem + RMN_OFF);       // [16]
    float*    rowT   = (float*)(smem + RT_OFF);        // [16]
    int*      rowB   = (int*)(smem + RB_OFF);          // [16]
    int*      rowNeed= (int*)(smem + RN_OFF);          // [16]
    int*      rowcnt = (int*)(smem + RC_OFF);          // [16]

    const int dir = blockIdx.z;
    const short* Qp = dir ? QpY : QpX;
    const short* Kp = dir ? KpX : KpY;
    const short* Vt = dir ? VtX : VtY;
    const int bh = blockIdx.y;
    const int qb = blockIdx.x;                // 0..63 (16-row q blocks)
    const int tid = threadIdx.x;
    const int lane = tid & 63;
    const int w = tid >> 6;                   // 0..7 : 128-col chunk in QK^T
    const int l15 = lane & 15, g = lane >> 4;

    // ---- Q fragments (hi/lo), rows qb*16 .. +16 ----
    bfx8 qf[2][2];
    {
        const short* qbase = Qp + ((size_t)bh * 1024 + qb * 16 + l15) * 128;
        #pragma unroll
        for (int ks = 0; ks < 2; ks++)
            #pragma unroll
            for (int p = 0; p < 2; p++)
                qf[ks][p] = *(const bfx8*)(qbase + p * 64 + ks * 32 + g * 8);
    }

    // ---- Phase S: S[16 rows][128 cols] per wave, K double-buffered ----
    fx4 acc[8];
    {
        const fx4 z4 = {0.f, 0.f, 0.f, 0.f};
        #pragma unroll
        for (int t = 0; t < 8; t++) acc[t] = z4;
        const short* kbase = Kp + ((size_t)bh * 1024 + w * 128 + l15) * 128 + g * 8;
        bfx8 kh0 = *(const bfx8*)(kbase);
        bfx8 kh1 = *(const bfx8*)(kbase + 32);
        bfx8 kl0 = *(const bfx8*)(kbase + 64);
        bfx8 kl1 = *(const bfx8*)(kbase + 96);
        #pragma unroll
        for (int t = 0; t < 8; t++) {
            bfx8 nh0, nh1, nl0, nl1;
            if (t < 7) {
                const short* nb = kbase + (t + 1) * 2048;
                nh0 = *(const bfx8*)(nb);
                nh1 = *(const bfx8*)(nb + 32);
                nl0 = *(const bfx8*)(nb + 64);
                nl1 = *(const bfx8*)(nb + 96);
            }
            acc[t] = __builtin_amdgcn_mfma_f32_16x16x32_bf16(qf[0][0], kh0, acc[t], 0, 0, 0);
            acc[t] = __builtin_amdgcn_mfma_f32_16x16x32_bf16(qf[0][0], kl0, acc[t], 0, 0, 0);
            acc[t] = __builtin_amdgcn_mfma_f32_16x16x32_bf16(qf[0][1], kh0, acc[t], 0, 0, 0);
            acc[t] = __builtin_amdgcn_mfma_f32_16x16x32_bf16(qf[1][0], kh1, acc[t], 0, 0, 0);
            acc[t] = __builtin_amdgcn_mfma_f32_16x16x32_bf16(qf[1][0], kl1, acc[t], 0, 0, 0);
            acc[t] = __builtin_amdgcn_mfma_f32_16x16x32_bf16(qf[1][1], kh1, acc[t], 0, 0, 0);
            kh0 = nh0; kh1 = nh1; kl0 = nl0; kl1 = nl1;
        }
    }
    // lane holds S rows (g*4 + r), cols (w*128 + t*16 + l15)

    // ---- Phase A: per-row max/min ----
    #pragma unroll
    for (int r = 0; r < 4; r++) {
        float a = acc[0][r], b = acc[0][r];
        #pragma unroll
        for (int t = 1; t < 8; t++) { a = fmaxf(a, acc[t][r]); b = fminf(b, acc[t][r]); }
        #pragma unroll
        for (int o = 1; o < 16; o <<= 1) { a = fmaxf(a, __shfl_xor(a, o)); b = fminf(b, __shfl_xor(b, o)); }
        if (l15 == 0) {
            int lrow = g * 4 + r;
            partmx[lrow * 8 + w] = a;
            partmn[lrow * 8 + w] = b;
        }
    }
    for (int i = tid; i < 16 * 96; i += 512) histU[i] = 0;
    if (tid < 16) rowcnt[tid] = 0;
    __syncthreads();   // B1

    float mxr[4], mnr[4], invr[4];
    #pragma unroll
    for (int r = 0; r < 4; r++) {
        int lrow = g * 4 + r;
        float a = partmx[lrow * 8 + 0], b = partmn[lrow * 8 + 0];
        #pragma unroll
        for (int j = 1; j < 8; j++) { a = fmaxf(a, partmx[lrow * 8 + j]); b = fminf(b, partmn[lrow * 8 + j]); }
        mxr[r] = a; mnr[r] = b;
        invr[r] = (a - b > 1e-30f) ? 96.0f / (a - b) : 0.0f;
        if (w == 0 && l15 == 0) { rowMx[lrow] = a; rowMn[lrow] = b; }
    }
    // ---- Phase B: histogram ----
    #pragma unroll
    for (int r = 0; r < 4; r++) {
        int lrow = g * 4 + r;
        #pragma unroll
        for (int t = 0; t < 8; t++) {
            int bin = (int)((acc[t][r] - mnr[r]) * invr[r]);
            bin = bin < 0 ? 0 : (bin > 95 ? 95 : bin);
            atomicAdd(&histU[lrow * 96 + bin], 1u);
        }
    }
    __syncthreads();   // B2

    // ---- Phase C: threshold bin + in-bin rank needed (2 rows per wave) ----
    #pragma unroll
    for (int rr = 0; rr < 2; rr++) {
        int row = w * 2 + rr;
        unsigned c0 = 0, c1 = 0;
        if (lane < 48) { c0 = histU[row * 96 + 2 * lane]; c1 = histU[row * 96 + 2 * lane + 1]; }
        unsigned ts = c0 + c1;
        #pragma unroll
        for (int o = 1; o < 64; o <<= 1) {
            unsigned u = __shfl_down(ts, o);
            if (lane + o < 64) ts += u;
        }
        unsigned ca_lo = ts - c0, ca_hi = ts - c0 - c1;
        bool oklo = (lane < 48) && (ca_lo < 256u) && (ca_lo + c0 >= 256u);
        bool okhi = (lane < 48) && (ca_hi < 256u) && (ca_hi + c1 >= 256u);
        unsigned long long bal = __ballot(oklo || okhi);
        int sl = __ffsll((long long)bal) - 1;
        int myB = oklo ? 2 * lane : 2 * lane + 1;
        int myNeed = 256 - (int)(oklo ? ca_lo : ca_hi);
        int B = __shfl(myB, sl);
        int need = __shfl(myNeed, sl);
        if (lane == 0) {
            float mr = rowMx[row], nr = rowMn[row];
            if (mr - nr < 1e-30f) { rowB[row] = -1; rowT[row] = nr; rowNeed[row] = 1; }
            else { rowB[row] = B; rowNeed[row] = need; }
        }
    }
    __syncthreads();   // B3

    // ---- Phase D: gather threshold-bin candidates ----
    #pragma unroll
    for (int r = 0; r < 4; r++) {
        int lrow = g * 4 + r;
        int B = rowB[lrow];
        #pragma unroll
        for (int t = 0; t < 8; t++) {
            int bin = (int)((acc[t][r] - mnr[r]) * invr[r]);
            bin = bin < 0 ? 0 : (bin > 95 ? 95 : bin);
            if (B >= 0 && bin == B) {
                int idx = atomicAdd(&rowcnt[lrow], 1);
                if (idx < 64) candF[lrow * 64 + idx] = acc[t][r];
            }
        }
    }
    __syncthreads();   // B4

    // ---- Phase E: exact rank among candidates (2 rows per wave) ----
    #pragma unroll
    for (int rr = 0; rr < 2; rr++) {
        int row = w * 2 + rr;
        int B = rowB[row];
        if (B < 0) continue;
        int m = rowcnt[row]; m = m > 64 ? 64 : m;
        int need = rowNeed[row];
        const float* crow = candF + row * 64;
        float v0 = (lane < m) ? crow[lane] : 0.f;
        int cg = 0, ce = 0;
        for (int i = 0; i < m; i++) {
            float c = crow[i];
            cg += (c > v0); ce += (c == v0);
        }
        bool ok = (lane < m) && (cg < need) && (need <= cg + ce);
        unsigned long long bal = __ballot(ok);
        float tt;
        if (bal) tt = __shfl(v0, __ffsll((long long)bal) - 1);
        else     tt = rowMn[row] + (float)B * (rowMx[row] - rowMn[row]) * (1.0f / 96.0f);
        if (lane == 0) rowT[row] = tt;
    }
    __syncthreads();   // B5

    // ---- Phase F: softmax numerators -> swizzled bf16 Pbuf + row sums ----
    #pragma unroll
    for (int r = 0; r < 4; r++) {
        int lrow = g * 4 + r;
        float tthr = rowT[lrow];
        float s = 0.f;
        unsigned sw = (unsigned)((lrow & 7) << 4);
        #pragma unroll
        for (int t = 0; t < 8; t++) {
            float v = acc[t][r];
            float p = (v >= tthr) ? __expf(v - mxr[r]) : 0.f;
            s += p;
            int col = w * 128 + t * 16 + l15;
            *(short*)(smem + (size_t)lrow * 2048 + (((unsigned)(col * 2)) ^ sw)) = f2bf(p);
        }
        #pragma unroll
        for (int o = 1; o < 16; o <<= 1) s += __shfl_xor(s, o);
        if (l15 == 0) partsum[lrow * 8 + w] = s;
    }
    __syncthreads();   // B6

    // ---- Phase G: inner = (P @ V) * inv_denom ; k split across wave pairs ----
    {
        const int ws = w & 3;     // d-group
        const int kh = w >> 2;    // k half (512 cols each)
        const short* vrow = Vt + ((size_t)bh * 64 + ws * 16 + l15) * 1024 + kh * 512;
        const char* pbase = smem + (size_t)l15 * 2048;
        const unsigned sw = (unsigned)((l15 & 7) << 4);
        fx4 acc0 = {0.f, 0.f, 0.f, 0.f}, acc1 = {0.f, 0.f, 0.f, 0.f};
        #pragma unroll
        for (int ks = 0; ks < 16; ks += 2) {
            bfx8 pa0 = *(const bfx8*)(pbase + (((unsigned)(kh * 1024 + ks * 64 + g * 16)) ^ sw));
            bfx8 vv0 = *(const bfx8*)(vrow + ks * 32 + g * 8);
            bfx8 pa1 = *(const bfx8*)(pbase + (((unsigned)(kh * 1024 + (ks + 1) * 64 + g * 16)) ^ sw));
            bfx8 vv1 = *(const bfx8*)(vrow + (ks + 1) * 32 + g * 8);
            acc0 = __builtin_amdgcn_mfma_f32_16x16x32_bf16(pa0, vv0, acc0, 0, 0, 0);
            acc1 = __builtin_amdgcn_mfma_f32_16x16x32_bf16(pa1, vv1, acc1, 0, 0, 0);
        }
        if (kh == 1) {
            float4 pv;
            pv.x = acc0[0] + acc1[0]; pv.y = acc0[1] + acc1[1];
            pv.z = acc0[2] + acc1[2]; pv.w = acc0[3] + acc1[3];
            *(float4*)&psumPV[(ws * 64 + lane) * 4] = pv;
        }
        __syncthreads();   // B7
        if (kh == 0) {
            const float4 other = *(const float4*)&psumPV[(ws * 64 + lane) * 4];
            float oth[4] = {other.x, other.y, other.z, other.w};
            #pragma unroll
            for (int r = 0; r < 4; r++) {
                int qrow = g * 4 + r;
                float denom = partsum[qrow * 8 + 0] + partsum[qrow * 8 + 1] +
                              partsum[qrow * 8 + 2] + partsum[qrow * 8 + 3] +
                              partsum[qrow * 8 + 4] + partsum[qrow * 8 + 5] +
                              partsum[qrow * 8 + 6] + partsum[qrow * 8 + 7];
                float v = (acc0[r] + acc1[r] + oth[r]) / denom;
                size_t orow = (size_t)dir * 8192 + (size_t)(bh >> 3) * 1024 + qb * 16 + qrow;
                inner[orow * 512 + (bh & 7) * 64 + ws * 16 + l15] = f2bf(v);
            }
        }
    }
}

// ==========================================================================
// Kernel 4: out = inner @ wout + bout   (plain bf16 MFMA)
// ==========================================================================
__global__ __launch_bounds__(256) void outproj_kernel(
    const short* __restrict__ inner, const float* __restrict__ wout,
    const float* __restrict__ bout, float* __restrict__ out)
{
    const int mb = blockIdx.x;   // 0..127
    const int nb = blockIdx.y;   // 0..3
    const int tid = threadIdx.x;
    const int lane = tid & 63;
    const int w = tid >> 6, wm = w >> 1, wn = w & 1;
    const int l15 = lane & 15, g8 = (lane >> 4) * 8;

    __shared__ short As[128][40];
    __shared__ short Bs[128][40];

    fx4 acc[4][4];
    const fx4 z4 = {0.f, 0.f, 0.f, 0.f};
    for (int i = 0; i < 4; i++) for (int j = 0; j < 4; j++) acc[i][j] = z4;

    const int arow = tid >> 1, ahalf = (tid & 1) * 16;
    const int bk = tid >> 3, bnseg = (tid & 7) * 16;

    for (int kb = 0; kb < 512; kb += 32) {
        __syncthreads();
        {
            const short* src = inner + (size_t)(mb * 128 + arow) * 512 + kb + ahalf;
            bfx8 v0 = *(const bfx8*)src, v1 = *(const bfx8*)(src + 8);
            *(bfx8*)&As[arow][ahalf] = v0;
            *(bfx8*)&As[arow][ahalf + 8] = v1;
        }
        {
            const float* src = wout + (size_t)(kb + bk) * 512 + nb * 128 + bnseg;
            #pragma unroll
            for (int q = 0; q < 4; q++) {
                float4 v = *(const float4*)(src + q * 4);
                float vv[4] = {v.x, v.y, v.z, v.w};
                #pragma unroll
                for (int c = 0; c < 4; c++) Bs[bnseg + q * 4 + c][bk] = f2bf(vv[c]);
            }
        }
        __syncthreads();
        bfx8 af[4], bf[4];
        #pragma unroll
        for (int mt = 0; mt < 4; mt++) af[mt] = *(bfx8*)&As[wm * 64 + mt * 16 + l15][g8];
        #pragma unroll
        for (int nt = 0; nt < 4; nt++) bf[nt] = *(bfx8*)&Bs[wn * 64 + nt * 16 + l15][g8];
        #pragma unroll
        for (int mt = 0; mt < 4; mt++)
            #pragma unroll
            for (int nt = 0; nt < 4; nt++)
                acc[mt][nt] = __builtin_amdgcn_mfma_f32_16x16x32_bf16(af[mt], bf[nt], acc[mt][nt], 0, 0, 0);
    }
    #pragma unroll
    for (int mt = 0; mt < 4; mt++)
        #pragma unroll
        for (int nt = 0; nt < 4; nt++)
            #pragma unroll
            for (int r = 0; r < 4; r++) {
                int row = mb * 128 + wm * 64 + mt * 16 + (lane >> 4) * 4 + r;
                int col = nb * 128 + wn * 64 + nt * 16 + l15;
                out[(size_t)row * 512 + col] = acc[mt][nt][r] + bout[col];
            }
}

// ==========================================================================
extern "C" void kernel_launch(void* const* d_in, const int* in_sizes, int n_in,
                              void* d_out, int out_size, void* d_ws, size_t ws_size,
                              hipStream_t stream)
{
    const float* x    = (const float*)d_in[0];
    const float* y    = (const float*)d_in[1];
    const float* wq   = (const float*)d_in[2];
    const float* wkv  = (const float*)d_in[3];
    const float* wout = (const float*)d_in[4];
    const float* bout = (const float*)d_in[5];
    float* out = (float*)d_out;

    char* ws = (char*)d_ws;
    size_t off = 0;
    auto alloc = [&](size_t bytes) -> void* {
        void* p = ws + off; off += (bytes + 255) & ~(size_t)255; return p;
    };
    const size_t QP = (size_t)8 * 8 * 1024 * 128 * 2;   // 16.78 MB
    const size_t VB = (size_t)8192 * 512 * 2;           // 8.39 MB
    short* QpX = (short*)alloc(QP);
    short* KpX = (short*)alloc(QP);
    short* QpY = (short*)alloc(QP);
    short* KpY = (short*)alloc(QP);
    short* VbX = (short*)alloc(VB);
    short* VbY = (short*)alloc(VB);
    short* VtX = (short*)alloc(VB);
    short* VtY = (short*)alloc(VB);
    short* inner = (short*)alloc((size_t)2 * 8192 * 512 * 2);
    if (off > ws_size) return;

    proj_kernel<<<dim3(64, 12, 2), 256, 0, stream>>>(x, y, wq, wkv, QpX, KpX, VbX, QpY, KpY, VbY);
    transv_kernel<<<dim3(16, 64, 2), 256, 0, stream>>>(VbX, VbY, VtX, VtY);
    (void)hipFuncSetAttribute((const void*)attn_kernel,
                              hipFuncAttributeMaxDynamicSharedMemorySize, ATTN_LDS);
    attn_kernel<<<dim3(64, 64, 2), 512, ATTN_LDS, stream>>>(QpX, KpX, VtX, QpY, KpY, VtY, inner);
    outproj_kernel<<<dim3(128, 4, 1), 256, 0, stream>>>(inner, wout, bout, out);
}

// Round 10
// 799.303 us; speedup vs baseline: 1.4924x; 1.4924x over previous
//
#include <hip/hip_runtime.h>
#include <hip/hip_bf16.h>

// ---------- types ----------
typedef __attribute__((ext_vector_type(8))) short bfx8;   // 8 bf16 in 4 VGPRs
typedef __attribute__((ext_vector_type(4))) float fx4;    // MFMA accumulator

__device__ __forceinline__ short f2bf(float f) {
    union { float f; unsigned u; } v; v.f = f;
    unsigned r = v.u + 0x7fffu + ((v.u >> 16) & 1u);      // RNE
    return (short)(r >> 16);
}
__device__ __forceinline__ float bf2f(short b) {
    union { unsigned u; float f; } v; v.u = ((unsigned)(unsigned short)b) << 16; return v.f;
}

// ==========================================================================
// Kernel 1: projection GEMM with f32->bf16 hi/lo split (3-term MFMA).
// ==========================================================================
__global__ __launch_bounds__(256) void proj_kernel(
    const float* __restrict__ X, const float* __restrict__ Y,
    const float* __restrict__ wq, const float* __restrict__ wkv,
    short* __restrict__ QpX, short* __restrict__ KpX, short* __restrict__ VbX,
    short* __restrict__ QpY, short* __restrict__ KpY, short* __restrict__ VbY)
{
    const int inp = blockIdx.z;
    const float* A = inp ? Y : X;
    short* Qp = inp ? QpY : QpX;
    short* Kp = inp ? KpY : KpX;
    short* Vb = inp ? VbY : VbX;
    const int mb = blockIdx.x;          // 0..63  (M tiles of 128)
    const int nb = blockIdx.y;          // 0..11  (N tiles of 128)
    const int tid = threadIdx.x;
    const int lane = tid & 63;
    const int w = tid >> 6, wm = w >> 1, wn = w & 1;
    const int l15 = lane & 15, g8 = (lane >> 4) * 8;

    __shared__ short As[128][72];   // [row][k_hi 0..31 | k_lo 32..63 | pad]
    __shared__ short Bs[128][72];   // [col][k_hi | k_lo | pad]  (W transposed)

    const float* Bsrc; int ldb, nbase0;
    if (nb < 4) { Bsrc = wq;  ldb = 512;  nbase0 = nb * 128; }
    else        { Bsrc = wkv; ldb = 1024; nbase0 = nb * 128 - 512; }

    fx4 acc[4][4];
    const fx4 z4 = {0.f, 0.f, 0.f, 0.f};
    for (int i = 0; i < 4; i++) for (int j = 0; j < 4; j++) acc[i][j] = z4;

    const int arow = tid >> 1, ahalf = (tid & 1) * 16;
    const int bk = tid >> 3, bnseg = (tid & 7) * 16;

    for (int kb = 0; kb < 512; kb += 32) {
        __syncthreads();
        { // stage A (hi/lo split)
            const float* src = A + (size_t)(mb * 128 + arow) * 512 + kb + ahalf;
            bfx8 h0, h1, l0, l1;
            #pragma unroll
            for (int q = 0; q < 4; q++) {
                float4 v = *(const float4*)(src + q * 4);
                float vv[4] = {v.x, v.y, v.z, v.w};
                #pragma unroll
                for (int c = 0; c < 4; c++) {
                    int idx = q * 4 + c;
                    short h = f2bf(vv[c]);
                    short l = f2bf(vv[c] - bf2f(h));
                    if (idx < 8) { h0[idx] = h; l0[idx] = l; }
                    else         { h1[idx - 8] = h; l1[idx - 8] = l; }
                }
            }
            *(bfx8*)&As[arow][ahalf] = h0;      *(bfx8*)&As[arow][ahalf + 8] = h1;
            *(bfx8*)&As[arow][32 + ahalf] = l0; *(bfx8*)&As[arow][32 + ahalf + 8] = l1;
        }
        { // stage B transposed (hi/lo split)
            const float* src = Bsrc + (size_t)(kb + bk) * ldb + nbase0 + bnseg;
            #pragma unroll
            for (int q = 0; q < 4; q++) {
                float4 v = *(const float4*)(src + q * 4);
                float vv[4] = {v.x, v.y, v.z, v.w};
                #pragma unroll
                for (int c = 0; c < 4; c++) {
                    int n = bnseg + q * 4 + c;
                    short h = f2bf(vv[c]);
                    Bs[n][bk] = h;
                    Bs[n][32 + bk] = f2bf(vv[c] - bf2f(h));
                }
            }
        }
        __syncthreads();
        bfx8 ah[4], al[4], bh[4], bl[4];
        #pragma unroll
        for (int mt = 0; mt < 4; mt++) {
            int r = wm * 64 + mt * 16 + l15;
            ah[mt] = *(bfx8*)&As[r][g8];
            al[mt] = *(bfx8*)&As[r][32 + g8];
        }
        #pragma unroll
        for (int nt = 0; nt < 4; nt++) {
            int r = wn * 64 + nt * 16 + l15;
            bh[nt] = *(bfx8*)&Bs[r][g8];
            bl[nt] = *(bfx8*)&Bs[r][32 + g8];
        }
        #pragma unroll
        for (int mt = 0; mt < 4; mt++)
            #pragma unroll
            for (int nt = 0; nt < 4; nt++) {
                acc[mt][nt] = __builtin_amdgcn_mfma_f32_16x16x32_bf16(ah[mt], bh[nt], acc[mt][nt], 0, 0, 0);
                acc[mt][nt] = __builtin_amdgcn_mfma_f32_16x16x32_bf16(ah[mt], bl[nt], acc[mt][nt], 0, 0, 0);
                acc[mt][nt] = __builtin_amdgcn_mfma_f32_16x16x32_bf16(al[mt], bh[nt], acc[mt][nt], 0, 0, 0);
            }
    }
    // epilogue: scatter to packed buffers
    #pragma unroll
    for (int mt = 0; mt < 4; mt++)
        #pragma unroll
        for (int nt = 0; nt < 4; nt++)
            #pragma unroll
            for (int r = 0; r < 4; r++) {
                int row = mb * 128 + wm * 64 + mt * 16 + (lane >> 4) * 4 + r;
                int col = nb * 128 + wn * 64 + nt * 16 + l15;
                float v = acc[mt][nt][r];
                int b = row >> 10, n = row & 1023;
                if (col < 512) {
                    v *= 0.125f;   // SCALE folded into Q (exact pow2)
                    int h = col >> 6, d = col & 63;
                    size_t base = ((size_t)(b * 8 + h) * 1024 + n) * 128;
                    short hi = f2bf(v);
                    Qp[base + d] = hi;
                    Qp[base + 64 + d] = f2bf(v - bf2f(hi));
                } else if (col < 1024) {
                    int cc = col - 512;
                    int h = cc >> 6, d = cc & 63;
                    size_t base = ((size_t)(b * 8 + h) * 1024 + n) * 128;
                    short hi = f2bf(v);
                    Kp[base + d] = hi;
                    Kp[base + 64 + d] = f2bf(v - bf2f(hi));
                } else {
                    Vb[(size_t)row * 512 + (col - 1024)] = f2bf(v);
                }
            }
}

// ==========================================================================
// Kernel 2: transpose V: Vb [8192][512] bf16 -> Vt [b*8+h][64][1024] bf16
// ==========================================================================
__global__ __launch_bounds__(256) void transv_kernel(
    const short* __restrict__ VbX, const short* __restrict__ VbY,
    short* __restrict__ VtX, short* __restrict__ VtY)
{
    const int inp = blockIdx.z;
    const short* Vb = inp ? VbY : VbX;
    short* Vt = inp ? VtY : VtX;
    const int bh = blockIdx.y, b = bh >> 3, h = bh & 7;
    const int nt = blockIdx.x;           // 0..15 (n tiles of 64)
    const int tid = threadIdx.x;
    __shared__ short tile[64][66];
    {
        int r = tid >> 2, c0 = (tid & 3) * 16;
        const short* src = Vb + ((size_t)(b * 1024 + nt * 64 + r)) * 512 + h * 64 + c0;
        bfx8 v0 = *(const bfx8*)src;
        bfx8 v1 = *(const bfx8*)(src + 8);
        #pragma unroll
        for (int i = 0; i < 8; i++) { tile[r][c0 + i] = v0[i]; tile[r][c0 + 8 + i] = v1[i]; }
    }
    __syncthreads();
    {
        int d = tid >> 2, n0 = (tid & 3) * 16;
        bfx8 o0, o1;
        #pragma unroll
        for (int i = 0; i < 8; i++) { o0[i] = tile[n0 + i][d]; o1[i] = tile[n0 + 8 + i][d]; }
        short* dst = Vt + ((size_t)(bh * 64 + d)) * 1024 + nt * 64 + n0;
        *(bfx8*)dst = o0;
        *(bfx8*)(dst + 8) = o1;
    }
}

// ==========================================================================
// Kernel 3 (v5): fused attention per (dir, b*8+h, 16-row q block).
// v4's LDS trim (40832B -> 4 blocks/CU) KEPT; register cap REVERTED to
// (512,4) (round 8 showed (512,8) -> VGPR 32 -> massive scratch spill,
// 3.2GB HBM traffic). At VGPR ~52 (round-4 measured) the HW still allows
// 8 waves/SIMD, so occupancy stays LDS-limited at 4 blocks/CU.
// ==========================================================================
#define PBUF_BYTES 32768              // 16 rows * 2048 B
#define HIST_OFF   32768              // 16*96*4 = 6144 (cand + psumPV alias here)
#define PMX_OFF    38912              // 16*8*4 = 512
#define PMN_OFF    39424              // 512
#define PSUM_OFF   39936              // 512
#define RMX_OFF    40448              // 64
#define RMN_OFF    40512              // 64
#define RT_OFF     40576              // 64
#define RB_OFF     40640              // 64
#define RN_OFF     40704              // 64
#define RC_OFF     40768              // 64
#define ATTN_LDS   40832

__global__ __launch_bounds__(512, 4) void attn_kernel(
    const short* __restrict__ QpX, const short* __restrict__ KpX, const short* __restrict__ VtX,
    const short* __restrict__ QpY, const short* __restrict__ KpY, const short* __restrict__ VtY,
    short* __restrict__ inner)
{
    extern __shared__ char smem[];
    unsigned* histU  = (unsigned*)(smem + HIST_OFF);   // [16][96]
    float*    candF  = (float*)(smem + HIST_OFF);      // [16][64] alias after hist dead
    float*    psumPV = (float*)(smem + HIST_OFF);      // [4][64][4] alias after cand dead
    float*    partmx = (float*)(smem + PMX_OFF);       // [16][8]
    float*    partmn = (float*)(smem + PMN_OFF);       // [16][8]
    float*    partsum= (float*)(smem + PSUM_OFF);      // [16][8]
    float*    rowMx  = (float*)(smem + RMX_OFF);       // [16]
    float*    rowMn  = (float*)(smem + RMN_OFF);       // [16]
    float*    rowT   = (float*)(smem + RT_OFF);        // [16]
    int*      rowB   = (int*)(smem + RB_OFF);          // [16]
    int*      rowNeed= (int*)(smem + RN_OFF);          // [16]
    int*      rowcnt = (int*)(smem + RC_OFF);          // [16]

    const int dir = blockIdx.z;
    const short* Qp = dir ? QpY : QpX;
    const short* Kp = dir ? KpX : KpY;
    const short* Vt = dir ? VtX : VtY;
    const int bh = blockIdx.y;
    const int qb = blockIdx.x;                // 0..63 (16-row q blocks)
    const int tid = threadIdx.x;
    const int lane = tid & 63;
    const int w = tid >> 6;                   // 0..7 : 128-col chunk in QK^T
    const int l15 = lane & 15, g = lane >> 4;

    // ---- Q fragments (hi/lo), rows qb*16 .. +16 ----
    bfx8 qf[2][2];
    {
        const short* qbase = Qp + ((size_t)bh * 1024 + qb * 16 + l15) * 128;
        #pragma unroll
        for (int ks = 0; ks < 2; ks++)
            #pragma unroll
            for (int p = 0; p < 2; p++)
                qf[ks][p] = *(const bfx8*)(qbase + p * 64 + ks * 32 + g * 8);
    }

    // ---- Phase S: S[16 rows][128 cols] per wave, K double-buffered ----
    fx4 acc[8];
    {
        const fx4 z4 = {0.f, 0.f, 0.f, 0.f};
        #pragma unroll
        for (int t = 0; t < 8; t++) acc[t] = z4;
        const short* kbase = Kp + ((size_t)bh * 1024 + w * 128 + l15) * 128 + g * 8;
        bfx8 kh0 = *(const bfx8*)(kbase);
        bfx8 kh1 = *(const bfx8*)(kbase + 32);
        bfx8 kl0 = *(const bfx8*)(kbase + 64);
        bfx8 kl1 = *(const bfx8*)(kbase + 96);
        #pragma unroll
        for (int t = 0; t < 8; t++) {
            bfx8 nh0, nh1, nl0, nl1;
            if (t < 7) {
                const short* nb = kbase + (t + 1) * 2048;
                nh0 = *(const bfx8*)(nb);
                nh1 = *(const bfx8*)(nb + 32);
                nl0 = *(const bfx8*)(nb + 64);
                nl1 = *(const bfx8*)(nb + 96);
            }
            acc[t] = __builtin_amdgcn_mfma_f32_16x16x32_bf16(qf[0][0], kh0, acc[t], 0, 0, 0);
            acc[t] = __builtin_amdgcn_mfma_f32_16x16x32_bf16(qf[0][0], kl0, acc[t], 0, 0, 0);
            acc[t] = __builtin_amdgcn_mfma_f32_16x16x32_bf16(qf[0][1], kh0, acc[t], 0, 0, 0);
            acc[t] = __builtin_amdgcn_mfma_f32_16x16x32_bf16(qf[1][0], kh1, acc[t], 0, 0, 0);
            acc[t] = __builtin_amdgcn_mfma_f32_16x16x32_bf16(qf[1][0], kl1, acc[t], 0, 0, 0);
            acc[t] = __builtin_amdgcn_mfma_f32_16x16x32_bf16(qf[1][1], kh1, acc[t], 0, 0, 0);
            kh0 = nh0; kh1 = nh1; kl0 = nl0; kl1 = nl1;
        }
    }
    // lane holds S rows (g*4 + r), cols (w*128 + t*16 + l15)

    // ---- Phase A: per-row max/min ----
    #pragma unroll
    for (int r = 0; r < 4; r++) {
        float a = acc[0][r], b = acc[0][r];
        #pragma unroll
        for (int t = 1; t < 8; t++) { a = fmaxf(a, acc[t][r]); b = fminf(b, acc[t][r]); }
        #pragma unroll
        for (int o = 1; o < 16; o <<= 1) { a = fmaxf(a, __shfl_xor(a, o)); b = fminf(b, __shfl_xor(b, o)); }
        if (l15 == 0) {
            int lrow = g * 4 + r;
            partmx[lrow * 8 + w] = a;
            partmn[lrow * 8 + w] = b;
        }
    }
    for (int i = tid; i < 16 * 96; i += 512) histU[i] = 0;
    if (tid < 16) rowcnt[tid] = 0;
    __syncthreads();   // B1

    float mxr[4], mnr[4], invr[4];
    #pragma unroll
    for (int r = 0; r < 4; r++) {
        int lrow = g * 4 + r;
        float a = partmx[lrow * 8 + 0], b = partmn[lrow * 8 + 0];
        #pragma unroll
        for (int j = 1; j < 8; j++) { a = fmaxf(a, partmx[lrow * 8 + j]); b = fminf(b, partmn[lrow * 8 + j]); }
        mxr[r] = a; mnr[r] = b;
        invr[r] = (a - b > 1e-30f) ? 96.0f / (a - b) : 0.0f;
        if (w == 0 && l15 == 0) { rowMx[lrow] = a; rowMn[lrow] = b; }
    }
    // ---- Phase B: histogram ----
    #pragma unroll
    for (int r = 0; r < 4; r++) {
        int lrow = g * 4 + r;
        #pragma unroll
        for (int t = 0; t < 8; t++) {
            int bin = (int)((acc[t][r] - mnr[r]) * invr[r]);
            bin = bin < 0 ? 0 : (bin > 95 ? 95 : bin);
            atomicAdd(&histU[lrow * 96 + bin], 1u);
        }
    }
    __syncthreads();   // B2

    // ---- Phase C: threshold bin + in-bin rank needed (2 rows per wave) ----
    #pragma unroll
    for (int rr = 0; rr < 2; rr++) {
        int row = w * 2 + rr;
        unsigned c0 = 0, c1 = 0;
        if (lane < 48) { c0 = histU[row * 96 + 2 * lane]; c1 = histU[row * 96 + 2 * lane + 1]; }
        unsigned ts = c0 + c1;
        #pragma unroll
        for (int o = 1; o < 64; o <<= 1) {
            unsigned u = __shfl_down(ts, o);
            if (lane + o < 64) ts += u;
        }
        unsigned ca_lo = ts - c0, ca_hi = ts - c0 - c1;
        bool oklo = (lane < 48) && (ca_lo < 256u) && (ca_lo + c0 >= 256u);
        bool okhi = (lane < 48) && (ca_hi < 256u) && (ca_hi + c1 >= 256u);
        unsigned long long bal = __ballot(oklo || okhi);
        int sl = __ffsll((long long)bal) - 1;
        int myB = oklo ? 2 * lane : 2 * lane + 1;
        int myNeed = 256 - (int)(oklo ? ca_lo : ca_hi);
        int B = __shfl(myB, sl);
        int need = __shfl(myNeed, sl);
        if (lane == 0) {
            float mr = rowMx[row], nr = rowMn[row];
            if (mr - nr < 1e-30f) { rowB[row] = -1; rowT[row] = nr; rowNeed[row] = 1; }
            else { rowB[row] = B; rowNeed[row] = need; }
        }
    }
    __syncthreads();   // B3

    // ---- Phase D: gather threshold-bin candidates ----
    #pragma unroll
    for (int r = 0; r < 4; r++) {
        int lrow = g * 4 + r;
        int B = rowB[lrow];
        #pragma unroll
        for (int t = 0; t < 8; t++) {
            int bin = (int)((acc[t][r] - mnr[r]) * invr[r]);
            bin = bin < 0 ? 0 : (bin > 95 ? 95 : bin);
            if (B >= 0 && bin == B) {
                int idx = atomicAdd(&rowcnt[lrow], 1);
                if (idx < 64) candF[lrow * 64 + idx] = acc[t][r];
            }
        }
    }
    __syncthreads();   // B4

    // ---- Phase E: exact rank among candidates (2 rows per wave) ----
    #pragma unroll
    for (int rr = 0; rr < 2; rr++) {
        int row = w * 2 + rr;
        int B = rowB[row];
        if (B < 0) continue;
        int m = rowcnt[row]; m = m > 64 ? 64 : m;
        int need = rowNeed[row];
        const float* crow = candF + row * 64;
        float v0 = (lane < m) ? crow[lane] : 0.f;
        int cg = 0, ce = 0;
        for (int i = 0; i < m; i++) {
            float c = crow[i];
            cg += (c > v0); ce += (c == v0);
        }
        bool ok = (lane < m) && (cg < need) && (need <= cg + ce);
        unsigned long long bal = __ballot(ok);
        float tt;
        if (bal) tt = __shfl(v0, __ffsll((long long)bal) - 1);
        else     tt = rowMn[row] + (float)B * (rowMx[row] - rowMn[row]) * (1.0f / 96.0f);
        if (lane == 0) rowT[row] = tt;
    }
    __syncthreads();   // B5

    // ---- Phase F: softmax numerators -> swizzled bf16 Pbuf + row sums ----
    #pragma unroll
    for (int r = 0; r < 4; r++) {
        int lrow = g * 4 + r;
        float tthr = rowT[lrow];
        float s = 0.f;
        unsigned sw = (unsigned)((lrow & 7) << 4);
        #pragma unroll
        for (int t = 0; t < 8; t++) {
            float v = acc[t][r];
            float p = (v >= tthr) ? __expf(v - mxr[r]) : 0.f;
            s += p;
            int col = w * 128 + t * 16 + l15;
            *(short*)(smem + (size_t)lrow * 2048 + (((unsigned)(col * 2)) ^ sw)) = f2bf(p);
        }
        #pragma unroll
        for (int o = 1; o < 16; o <<= 1) s += __shfl_xor(s, o);
        if (l15 == 0) partsum[lrow * 8 + w] = s;
    }
    __syncthreads();   // B6

    // ---- Phase G: inner = (P @ V) * inv_denom ; k split across wave pairs ----
    {
        const int ws = w & 3;     // d-group
        const int kh = w >> 2;    // k half (512 cols each)
        const short* vrow = Vt + ((size_t)bh * 64 + ws * 16 + l15) * 1024 + kh * 512;
        const char* pbase = smem + (size_t)l15 * 2048;
        const unsigned sw = (unsigned)((l15 & 7) << 4);
        fx4 acc0 = {0.f, 0.f, 0.f, 0.f}, acc1 = {0.f, 0.f, 0.f, 0.f};
        #pragma unroll
        for (int ks = 0; ks < 16; ks += 2) {
            bfx8 pa0 = *(const bfx8*)(pbase + (((unsigned)(kh * 1024 + ks * 64 + g * 16)) ^ sw));
            bfx8 vv0 = *(const bfx8*)(vrow + ks * 32 + g * 8);
            bfx8 pa1 = *(const bfx8*)(pbase + (((unsigned)(kh * 1024 + (ks + 1) * 64 + g * 16)) ^ sw));
            bfx8 vv1 = *(const bfx8*)(vrow + (ks + 1) * 32 + g * 8);
            acc0 = __builtin_amdgcn_mfma_f32_16x16x32_bf16(pa0, vv0, acc0, 0, 0, 0);
            acc1 = __builtin_amdgcn_mfma_f32_16x16x32_bf16(pa1, vv1, acc1, 0, 0, 0);
        }
        if (kh == 1) {
            float4 pv;
            pv.x = acc0[0] + acc1[0]; pv.y = acc0[1] + acc1[1];
            pv.z = acc0[2] + acc1[2]; pv.w = acc0[3] + acc1[3];
            *(float4*)&psumPV[(ws * 64 + lane) * 4] = pv;
        }
        __syncthreads();   // B7
        if (kh == 0) {
            const float4 other = *(const float4*)&psumPV[(ws * 64 + lane) * 4];
            float oth[4] = {other.x, other.y, other.z, other.w};
            #pragma unroll
            for (int r = 0; r < 4; r++) {
                int qrow = g * 4 + r;
                float denom = partsum[qrow * 8 + 0] + partsum[qrow * 8 + 1] +
                              partsum[qrow * 8 + 2] + partsum[qrow * 8 + 3] +
                              partsum[qrow * 8 + 4] + partsum[qrow * 8 + 5] +
                              partsum[qrow * 8 + 6] + partsum[qrow * 8 + 7];
                float v = (acc0[r] + acc1[r] + oth[r]) / denom;
                size_t orow = (size_t)dir * 8192 + (size_t)(bh >> 3) * 1024 + qb * 16 + qrow;
                inner[orow * 512 + (bh & 7) * 64 + ws * 16 + l15] = f2bf(v);
            }
        }
    }
}

// ==========================================================================
// Kernel 4: out = inner @ wout + bout   (plain bf16 MFMA)
// ==========================================================================
__global__ __launch_bounds__(256) void outproj_kernel(
    const short* __restrict__ inner, const float* __restrict__ wout,
    const float* __restrict__ bout, float* __restrict__ out)
{
    const int mb = blockIdx.x;   // 0..127
    const int nb = blockIdx.y;   // 0..3
    const int tid = threadIdx.x;
    const int lane = tid & 63;
    const int w = tid >> 6, wm = w >> 1, wn = w & 1;
    const int l15 = lane & 15, g8 = (lane >> 4) * 8;

    __shared__ short As[128][40];
    __shared__ short Bs[128][40];

    fx4 acc[4][4];
    const fx4 z4 = {0.f, 0.f, 0.f, 0.f};
    for (int i = 0; i < 4; i++) for (int j = 0; j < 4; j++) acc[i][j] = z4;

    const int arow = tid >> 1, ahalf = (tid & 1) * 16;
    const int bk = tid >> 3, bnseg = (tid & 7) * 16;

    for (int kb = 0; kb < 512; kb += 32) {
        __syncthreads();
        {
            const short* src = inner + (size_t)(mb * 128 + arow) * 512 + kb + ahalf;
            bfx8 v0 = *(const bfx8*)src, v1 = *(const bfx8*)(src + 8);
            *(bfx8*)&As[arow][ahalf] = v0;
            *(bfx8*)&As[arow][ahalf + 8] = v1;
        }
        {
            const float* src = wout + (size_t)(kb + bk) * 512 + nb * 128 + bnseg;
            #pragma unroll
            for (int q = 0; q < 4; q++) {
                float4 v = *(const float4*)(src + q * 4);
                float vv[4] = {v.x, v.y, v.z, v.w};
                #pragma unroll
                for (int c = 0; c < 4; c++) Bs[bnseg + q * 4 + c][bk] = f2bf(vv[c]);
            }
        }
        __syncthreads();
        bfx8 af[4], bf[4];
        #pragma unroll
        for (int mt = 0; mt < 4; mt++) af[mt] = *(bfx8*)&As[wm * 64 + mt * 16 + l15][g8];
        #pragma unroll
        for (int nt = 0; nt < 4; nt++) bf[nt] = *(bfx8*)&Bs[wn * 64 + nt * 16 + l15][g8];
        #pragma unroll
        for (int mt = 0; mt < 4; mt++)
            #pragma unroll
            for (int nt = 0; nt < 4; nt++)
                acc[mt][nt] = __builtin_amdgcn_mfma_f32_16x16x32_bf16(af[mt], bf[nt], acc[mt][nt], 0, 0, 0);
    }
    #pragma unroll
    for (int mt = 0; mt < 4; mt++)
        #pragma unroll
        for (int nt = 0; nt < 4; nt++)
            #pragma unroll
            for (int r = 0; r < 4; r++) {
                int row = mb * 128 + wm * 64 + mt * 16 + (lane >> 4) * 4 + r;
                int col = nb * 128 + wn * 64 + nt * 16 + l15;
                out[(size_t)row * 512 + col] = acc[mt][nt][r] + bout[col];
            }
}

// ==========================================================================
extern "C" void kernel_launch(void* const* d_in, const int* in_sizes, int n_in,
                              void* d_out, int out_size, void* d_ws, size_t ws_size,
                              hipStream_t stream)
{
    const float* x    = (const float*)d_in[0];
    const float* y    = (const float*)d_in[1];
    const float* wq   = (const float*)d_in[2];
    const float* wkv  = (const float*)d_in[3];
    const float* wout = (const float*)d_in[4];
    const float* bout = (const float*)d_in[5];
    float* out = (float*)d_out;

    char* ws = (char*)d_ws;
    size_t off = 0;
    auto alloc = [&](size_t bytes) -> void* {
        void* p = ws + off; off += (bytes + 255) & ~(size_t)255; return p;
    };
    const size_t QP = (size_t)8 * 8 * 1024 * 128 * 2;   // 16.78 MB
    const size_t VB = (size_t)8192 * 512 * 2;           // 8.39 MB
    short* QpX = (short*)alloc(QP);
    short* KpX = (short*)alloc(QP);
    short* QpY = (short*)alloc(QP);
    short* KpY = (short*)alloc(QP);
    short* VbX = (short*)alloc(VB);
    short* VbY = (short*)alloc(VB);
    short* VtX = (short*)alloc(VB);
    short* VtY = (short*)alloc(VB);
    short* inner = (short*)alloc((size_t)2 * 8192 * 512 * 2);
    if (off > ws_size) return;

    proj_kernel<<<dim3(64, 12, 2), 256, 0, stream>>>(x, y, wq, wkv, QpX, KpX, VbX, QpY, KpY, VbY);
    transv_kernel<<<dim3(16, 64, 2), 256, 0, stream>>>(VbX, VbY, VtX, VtY);
    (void)hipFuncSetAttribute((const void*)attn_kernel,
                              hipFuncAttributeMaxDynamicSharedMemorySize, ATTN_LDS);
    attn_kernel<<<dim3(64, 64, 2), 512, ATTN_LDS, stream>>>(QpX, KpX, VtX, QpY, KpY, VtY, inner);
    outproj_kernel<<<dim3(128, 4, 1), 256, 0, stream>>>(inner, wout, bout, out);
}

// Round 12
// 789.607 us; speedup vs baseline: 1.5108x; 1.0123x over previous
//
#include <hip/hip_runtime.h>
#include <hip/hip_bf16.h>

// ---------- types ----------
typedef __attribute__((ext_vector_type(8))) short bfx8;   // 8 bf16 in 4 VGPRs
typedef __attribute__((ext_vector_type(4))) short sx4;    // 4 bf16
typedef __attribute__((ext_vector_type(4))) float fx4;    // MFMA accumulator

__device__ __forceinline__ short f2bf(float f) {
    union { float f; unsigned u; } v; v.f = f;
    unsigned r = v.u + 0x7fffu + ((v.u >> 16) & 1u);      // RNE
    return (short)(r >> 16);
}
__device__ __forceinline__ float bf2f(short b) {
    union { unsigned u; float f; } v; v.u = ((unsigned)(unsigned short)b) << 16; return v.f;
}

// DPP row_ror over the 16-lane row (VALU pipe; avoids ds_bpermute shfl)
template<int CTRL>
__device__ __forceinline__ float dppf(float x) {
    return __int_as_float(__builtin_amdgcn_update_dpp(0, __float_as_int(x), CTRL, 0xF, 0xF, false));
}
__device__ __forceinline__ float rowmax16(float a) {
    a = fmaxf(a, dppf<0x121>(a)); a = fmaxf(a, dppf<0x122>(a));
    a = fmaxf(a, dppf<0x124>(a)); a = fmaxf(a, dppf<0x128>(a));
    return a;
}
__device__ __forceinline__ float rowmin16(float a) {
    a = fminf(a, dppf<0x121>(a)); a = fminf(a, dppf<0x122>(a));
    a = fminf(a, dppf<0x124>(a)); a = fminf(a, dppf<0x128>(a));
    return a;
}
__device__ __forceinline__ float rowsum16(float a) {
    a += dppf<0x121>(a); a += dppf<0x122>(a);
    a += dppf<0x124>(a); a += dppf<0x128>(a);
    return a;
}

// ==========================================================================
// Kernel 1: projection GEMM with f32->bf16 hi/lo split (3-term MFMA).
// ==========================================================================
__global__ __launch_bounds__(256) void proj_kernel(
    const float* __restrict__ X, const float* __restrict__ Y,
    const float* __restrict__ wq, const float* __restrict__ wkv,
    short* __restrict__ QpX, short* __restrict__ KpX, short* __restrict__ VbX,
    short* __restrict__ QpY, short* __restrict__ KpY, short* __restrict__ VbY)
{
    const int inp = blockIdx.z;
    const float* A = inp ? Y : X;
    short* Qp = inp ? QpY : QpX;
    short* Kp = inp ? KpY : KpX;
    short* Vb = inp ? VbY : VbX;
    const int mb = blockIdx.x;          // 0..63  (M tiles of 128)
    const int nb = blockIdx.y;          // 0..11  (N tiles of 128)
    const int tid = threadIdx.x;
    const int lane = tid & 63;
    const int w = tid >> 6, wm = w >> 1, wn = w & 1;
    const int l15 = lane & 15, g8 = (lane >> 4) * 8;

    __shared__ short As[128][72];   // [row][k_hi 0..31 | k_lo 32..63 | pad]
    __shared__ short Bs[128][72];   // [col][k_hi | k_lo | pad]  (W transposed)

    const float* Bsrc; int ldb, nbase0;
    if (nb < 4) { Bsrc = wq;  ldb = 512;  nbase0 = nb * 128; }
    else        { Bsrc = wkv; ldb = 1024; nbase0 = nb * 128 - 512; }

    fx4 acc[4][4];
    const fx4 z4 = {0.f, 0.f, 0.f, 0.f};
    for (int i = 0; i < 4; i++) for (int j = 0; j < 4; j++) acc[i][j] = z4;

    const int arow = tid >> 1, ahalf = (tid & 1) * 16;
    const int bk = tid >> 3, bnseg = (tid & 7) * 16;

    for (int kb = 0; kb < 512; kb += 32) {
        __syncthreads();
        { // stage A (hi/lo split)
            const float* src = A + (size_t)(mb * 128 + arow) * 512 + kb + ahalf;
            bfx8 h0, h1, l0, l1;
            #pragma unroll
            for (int q = 0; q < 4; q++) {
                float4 v = *(const float4*)(src + q * 4);
                float vv[4] = {v.x, v.y, v.z, v.w};
                #pragma unroll
                for (int c = 0; c < 4; c++) {
                    int idx = q * 4 + c;
                    short h = f2bf(vv[c]);
                    short l = f2bf(vv[c] - bf2f(h));
                    if (idx < 8) { h0[idx] = h; l0[idx] = l; }
                    else         { h1[idx - 8] = h; l1[idx - 8] = l; }
                }
            }
            *(bfx8*)&As[arow][ahalf] = h0;      *(bfx8*)&As[arow][ahalf + 8] = h1;
            *(bfx8*)&As[arow][32 + ahalf] = l0; *(bfx8*)&As[arow][32 + ahalf + 8] = l1;
        }
        { // stage B transposed (hi/lo split)
            const float* src = Bsrc + (size_t)(kb + bk) * ldb + nbase0 + bnseg;
            #pragma unroll
            for (int q = 0; q < 4; q++) {
                float4 v = *(const float4*)(src + q * 4);
                float vv[4] = {v.x, v.y, v.z, v.w};
                #pragma unroll
                for (int c = 0; c < 4; c++) {
                    int n = bnseg + q * 4 + c;
                    short h = f2bf(vv[c]);
                    Bs[n][bk] = h;
                    Bs[n][32 + bk] = f2bf(vv[c] - bf2f(h));
                }
            }
        }
        __syncthreads();
        bfx8 ah[4], al[4], bh[4], bl[4];
        #pragma unroll
        for (int mt = 0; mt < 4; mt++) {
            int r = wm * 64 + mt * 16 + l15;
            ah[mt] = *(bfx8*)&As[r][g8];
            al[mt] = *(bfx8*)&As[r][32 + g8];
        }
        #pragma unroll
        for (int nt = 0; nt < 4; nt++) {
            int r = wn * 64 + nt * 16 + l15;
            bh[nt] = *(bfx8*)&Bs[r][g8];
            bl[nt] = *(bfx8*)&Bs[r][32 + g8];
        }
        #pragma unroll
        for (int mt = 0; mt < 4; mt++)
            #pragma unroll
            for (int nt = 0; nt < 4; nt++) {
                acc[mt][nt] = __builtin_amdgcn_mfma_f32_16x16x32_bf16(ah[mt], bh[nt], acc[mt][nt], 0, 0, 0);
                acc[mt][nt] = __builtin_amdgcn_mfma_f32_16x16x32_bf16(ah[mt], bl[nt], acc[mt][nt], 0, 0, 0);
                acc[mt][nt] = __builtin_amdgcn_mfma_f32_16x16x32_bf16(al[mt], bh[nt], acc[mt][nt], 0, 0, 0);
            }
    }
    // epilogue: scatter to packed buffers
    #pragma unroll
    for (int mt = 0; mt < 4; mt++)
        #pragma unroll
        for (int nt = 0; nt < 4; nt++)
            #pragma unroll
            for (int r = 0; r < 4; r++) {
                int row = mb * 128 + wm * 64 + mt * 16 + (lane >> 4) * 4 + r;
                int col = nb * 128 + wn * 64 + nt * 16 + l15;
                float v = acc[mt][nt][r];
                int b = row >> 10, n = row & 1023;
                if (col < 512) {
                    v *= 0.125f;   // SCALE folded into Q (exact pow2)
                    int h = col >> 6, d = col & 63;
                    size_t base = ((size_t)(b * 8 + h) * 1024 + n) * 128;
                    short hi = f2bf(v);
                    Qp[base + d] = hi;
                    Qp[base + 64 + d] = f2bf(v - bf2f(hi));
                } else if (col < 1024) {
                    int cc = col - 512;
                    int h = cc >> 6, d = cc & 63;
                    size_t base = ((size_t)(b * 8 + h) * 1024 + n) * 128;
                    short hi = f2bf(v);
                    Kp[base + d] = hi;
                    Kp[base + 64 + d] = f2bf(v - bf2f(hi));
                } else {
                    Vb[(size_t)row * 512 + (col - 1024)] = f2bf(v);
                }
            }
}

// ==========================================================================
// Kernel 2: transpose V with pi-permuted column order:
// Vt'[bh][d][p], p = w*128 + l15*8 + t  holds V[c][d], c = w*128 + t*16 + l15.
// (PV is invariant: P storage uses the same permutation.)
// ==========================================================================
__global__ __launch_bounds__(256) void transv_kernel(
    const short* __restrict__ VbX, const short* __restrict__ VbY,
    short* __restrict__ VtX, short* __restrict__ VtY)
{
    const int inp = blockIdx.z;
    const short* Vb = inp ? VbY : VbX;
    short* Vt = inp ? VtY : VtX;
    const int bh = blockIdx.y, b = bh >> 3, h = bh & 7;
    const int nt = blockIdx.x;           // 0..15 (c tiles of 64)
    const int tid = threadIdx.x;
    __shared__ short tile[64][66];       // [c_local][d]
    {
        int r = tid >> 2, c0 = (tid & 3) * 16;
        const short* src = Vb + ((size_t)(b * 1024 + nt * 64 + r)) * 512 + h * 64 + c0;
        bfx8 v0 = *(const bfx8*)src;
        bfx8 v1 = *(const bfx8*)(src + 8);
        #pragma unroll
        for (int i = 0; i < 8; i++) { tile[r][c0 + i] = v0[i]; tile[r][c0 + 8 + i] = v1[i]; }
    }
    __syncthreads();
    {
        const int d = tid >> 2, jj = tid & 3;
        const int w = nt >> 1, thalf = (nt & 1) * 4;
        short* dstrow = Vt + ((size_t)(bh * 64 + d)) * 1024 + w * 128 + thalf;
        #pragma unroll
        for (int it = 0; it < 4; ++it) {
            int l15 = (jj << 2) | it;
            sx4 v;
            v[0] = tile[l15][d];        // t'=0 -> c_local = 0*16+l15
            v[1] = tile[16 + l15][d];
            v[2] = tile[32 + l15][d];
            v[3] = tile[48 + l15][d];
            *(sx4*)(dstrow + l15 * 8) = v;
        }
    }
}

// ==========================================================================
// Kernel 3 (v6): fused attention, DS-diet:
//  - P stored pi-permuted -> Phase F emits ONE b128 LDS store per row
//  - 16-lane reductions via DPP row_ror (VALU) instead of __shfl_xor (DS)
//  - histogram stride 97 / cand stride 65 (bank de-alias for atomics)
// Selection arithmetic identical to v5. LDS 40896B, (512,4).
// ==========================================================================
#define HIST_OFF   32768              // hist [16][97] = 6208 (cand/psumPV alias)
#define PMX_OFF    38976              // 16*8*4 = 512
#define PMN_OFF    39488              // 512
#define PSUM_OFF   40000              // 512
#define RMX_OFF    40512              // 64
#define RMN_OFF    40576              // 64
#define RT_OFF     40640              // 64
#define RB_OFF     40704              // 64
#define RN_OFF     40768              // 64
#define RC_OFF     40832              // 64
#define ATTN_LDS   40896

__global__ __launch_bounds__(512, 4) void attn_kernel(
    const short* __restrict__ QpX, const short* __restrict__ KpX, const short* __restrict__ VtX,
    const short* __restrict__ QpY, const short* __restrict__ KpY, const short* __restrict__ VtY,
    short* __restrict__ inner)
{
    extern __shared__ char smem[];
    unsigned* histU  = (unsigned*)(smem + HIST_OFF);   // [16][97]
    float*    candF  = (float*)(smem + HIST_OFF);      // [16][65] alias after hist dead
    float*    psumPV = (float*)(smem + HIST_OFF);      // [4][64][4] alias after cand dead
    float*    partmx = (float*)(smem + PMX_OFF);       // [16][8]
    float*    partmn = (float*)(smem + PMN_OFF);       // [16][8]
    float*    partsum= (float*)(smem + PSUM_OFF);      // [16][8]
    float*    rowMx  = (float*)(smem + RMX_OFF);       // [16]
    float*    rowMn  = (float*)(smem + RMN_OFF);       // [16]
    float*    rowT   = (float*)(smem + RT_OFF);        // [16]
    int*      rowB   = (int*)(smem + RB_OFF);          // [16]
    int*      rowNeed= (int*)(smem + RN_OFF);          // [16]
    int*      rowcnt = (int*)(smem + RC_OFF);          // [16]

    const int dir = blockIdx.z;
    const short* Qp = dir ? QpY : QpX;
    const short* Kp = dir ? KpX : KpY;
    const short* Vt = dir ? VtX : VtY;
    const int bh = blockIdx.y;
    const int qb = blockIdx.x;                // 0..63 (16-row q blocks)
    const int tid = threadIdx.x;
    const int lane = tid & 63;
    const int w = tid >> 6;                   // 0..7 : 128-col chunk in QK^T
    const int l15 = lane & 15, g = lane >> 4;

    // ---- Q fragments (hi/lo), rows qb*16 .. +16 ----
    bfx8 qf[2][2];
    {
        const short* qbase = Qp + ((size_t)bh * 1024 + qb * 16 + l15) * 128;
        #pragma unroll
        for (int ks = 0; ks < 2; ks++)
            #pragma unroll
            for (int p = 0; p < 2; p++)
                qf[ks][p] = *(const bfx8*)(qbase + p * 64 + ks * 32 + g * 8);
    }

    // ---- Phase S: S[16 rows][128 cols] per wave, K double-buffered ----
    fx4 acc[8];
    {
        const fx4 z4 = {0.f, 0.f, 0.f, 0.f};
        #pragma unroll
        for (int t = 0; t < 8; t++) acc[t] = z4;
        const short* kbase = Kp + ((size_t)bh * 1024 + w * 128 + l15) * 128 + g * 8;
        bfx8 kh0 = *(const bfx8*)(kbase);
        bfx8 kh1 = *(const bfx8*)(kbase + 32);
        bfx8 kl0 = *(const bfx8*)(kbase + 64);
        bfx8 kl1 = *(const bfx8*)(kbase + 96);
        #pragma unroll
        for (int t = 0; t < 8; t++) {
            bfx8 nh0, nh1, nl0, nl1;
            if (t < 7) {
                const short* nb = kbase + (t + 1) * 2048;
                nh0 = *(const bfx8*)(nb);
                nh1 = *(const bfx8*)(nb + 32);
                nl0 = *(const bfx8*)(nb + 64);
                nl1 = *(const bfx8*)(nb + 96);
            }
            acc[t] = __builtin_amdgcn_mfma_f32_16x16x32_bf16(qf[0][0], kh0, acc[t], 0, 0, 0);
            acc[t] = __builtin_amdgcn_mfma_f32_16x16x32_bf16(qf[0][0], kl0, acc[t], 0, 0, 0);
            acc[t] = __builtin_amdgcn_mfma_f32_16x16x32_bf16(qf[0][1], kh0, acc[t], 0, 0, 0);
            acc[t] = __builtin_amdgcn_mfma_f32_16x16x32_bf16(qf[1][0], kh1, acc[t], 0, 0, 0);
            acc[t] = __builtin_amdgcn_mfma_f32_16x16x32_bf16(qf[1][0], kl1, acc[t], 0, 0, 0);
            acc[t] = __builtin_amdgcn_mfma_f32_16x16x32_bf16(qf[1][1], kh1, acc[t], 0, 0, 0);
            kh0 = nh0; kh1 = nh1; kl0 = nl0; kl1 = nl1;
        }
    }
    // lane holds S rows (g*4 + r), cols (w*128 + t*16 + l15)

    // ---- Phase A: per-row max/min (DPP reduce, no DS) ----
    #pragma unroll
    for (int r = 0; r < 4; r++) {
        float a = acc[0][r], b = acc[0][r];
        #pragma unroll
        for (int t = 1; t < 8; t++) { a = fmaxf(a, acc[t][r]); b = fminf(b, acc[t][r]); }
        a = rowmax16(a); b = rowmin16(b);
        if (l15 == 0) {
            int lrow = g * 4 + r;
            partmx[lrow * 8 + w] = a;
            partmn[lrow * 8 + w] = b;
        }
    }
    for (int i = tid; i < 16 * 97; i += 512) histU[i] = 0;
    if (tid < 16) rowcnt[tid] = 0;
    __syncthreads();   // B1

    float mxr[4], mnr[4], invr[4];
    #pragma unroll
    for (int r = 0; r < 4; r++) {
        int lrow = g * 4 + r;
        float a = partmx[lrow * 8 + 0], b = partmn[lrow * 8 + 0];
        #pragma unroll
        for (int j = 1; j < 8; j++) { a = fmaxf(a, partmx[lrow * 8 + j]); b = fminf(b, partmn[lrow * 8 + j]); }
        mxr[r] = a; mnr[r] = b;
        invr[r] = (a - b > 1e-30f) ? 96.0f / (a - b) : 0.0f;
        if (w == 0 && l15 == 0) { rowMx[lrow] = a; rowMn[lrow] = b; }
    }
    // ---- Phase B: histogram (stride-97 rows de-alias banks) ----
    #pragma unroll
    for (int r = 0; r < 4; r++) {
        int lrow = g * 4 + r;
        #pragma unroll
        for (int t = 0; t < 8; t++) {
            int bin = (int)((acc[t][r] - mnr[r]) * invr[r]);
            bin = bin < 0 ? 0 : (bin > 95 ? 95 : bin);
            atomicAdd(&histU[lrow * 97 + bin], 1u);
        }
    }
    __syncthreads();   // B2

    // ---- Phase C: threshold bin + in-bin rank needed (2 rows per wave) ----
    #pragma unroll
    for (int rr = 0; rr < 2; rr++) {
        int row = w * 2 + rr;
        unsigned c0 = 0, c1 = 0;
        if (lane < 48) { c0 = histU[row * 97 + 2 * lane]; c1 = histU[row * 97 + 2 * lane + 1]; }
        unsigned ts = c0 + c1;
        #pragma unroll
        for (int o = 1; o < 64; o <<= 1) {
            unsigned u = __shfl_down(ts, o);
            if (lane + o < 64) ts += u;
        }
        unsigned ca_lo = ts - c0, ca_hi = ts - c0 - c1;
        bool oklo = (lane < 48) && (ca_lo < 256u) && (ca_lo + c0 >= 256u);
        bool okhi = (lane < 48) && (ca_hi < 256u) && (ca_hi + c1 >= 256u);
        unsigned long long bal = __ballot(oklo || okhi);
        int sl = __ffsll((long long)bal) - 1;
        int myB = oklo ? 2 * lane : 2 * lane + 1;
        int myNeed = 256 - (int)(oklo ? ca_lo : ca_hi);
        int B = __shfl(myB, sl);
        int need = __shfl(myNeed, sl);
        if (lane == 0) {
            float mr = rowMx[row], nr = rowMn[row];
            if (mr - nr < 1e-30f) { rowB[row] = -1; rowT[row] = nr; rowNeed[row] = 1; }
            else { rowB[row] = B; rowNeed[row] = need; }
        }
    }
    __syncthreads();   // B3

    // ---- Phase D: gather threshold-bin candidates ----
    #pragma unroll
    for (int r = 0; r < 4; r++) {
        int lrow = g * 4 + r;
        int B = rowB[lrow];
        #pragma unroll
        for (int t = 0; t < 8; t++) {
            int bin = (int)((acc[t][r] - mnr[r]) * invr[r]);
            bin = bin < 0 ? 0 : (bin > 95 ? 95 : bin);
            if (B >= 0 && bin == B) {
                int idx = atomicAdd(&rowcnt[lrow], 1);
                if (idx < 64) candF[lrow * 65 + idx] = acc[t][r];
            }
        }
    }
    __syncthreads();   // B4

    // ---- Phase E: exact rank among candidates (2 rows per wave) ----
    #pragma unroll
    for (int rr = 0; rr < 2; rr++) {
        int row = w * 2 + rr;
        int B = rowB[row];
        if (B < 0) continue;
        int m = rowcnt[row]; m = m > 64 ? 64 : m;
        int need = rowNeed[row];
        const float* crow = candF + row * 65;
        float v0 = (lane < m) ? crow[lane] : 0.f;
        int cg = 0, ce = 0;
        for (int i = 0; i < m; i++) {
            float c = crow[i];
            cg += (c > v0); ce += (c == v0);
        }
        bool ok = (lane < m) && (cg < need) && (need <= cg + ce);
        unsigned long long bal = __ballot(ok);
        float tt;
        if (bal) tt = __shfl(v0, __ffsll((long long)bal) - 1);
        else     tt = rowMn[row] + (float)B * (rowMx[row] - rowMn[row]) * (1.0f / 96.0f);
        if (lane == 0) rowT[row] = tt;
    }
    __syncthreads();   // B5

    // ---- Phase F: softmax numerators -> ONE b128 store per row (pi layout) ----
    #pragma unroll
    for (int r = 0; r < 4; r++) {
        int lrow = g * 4 + r;
        float tthr = rowT[lrow];
        float s = 0.f;
        bfx8 pk;
        #pragma unroll
        for (int t = 0; t < 8; t++) {
            float v = acc[t][r];
            float p = (v >= tthr) ? __expf(v - mxr[r]) : 0.f;
            s += p;
            pk[t] = f2bf(p);   // p-position = w*128 + l15*8 + t
        }
        unsigned sw = (unsigned)((lrow & 7) << 4);
        *(bfx8*)(smem + (size_t)lrow * 2048 + (((unsigned)(w * 256 + l15 * 16)) ^ sw)) = pk;
        s = rowsum16(s);
        if (l15 == 0) partsum[lrow * 8 + w] = s;
    }
    __syncthreads();   // B6

    // ---- Phase G: inner = (P @ V) * inv_denom ; k split across wave pairs ----
    {
        const int ws = w & 3;     // d-group
        const int kh = w >> 2;    // p half (512 each)
        const short* vrow = Vt + ((size_t)bh * 64 + ws * 16 + l15) * 1024 + kh * 512;
        const char* pbase = smem + (size_t)l15 * 2048;
        const unsigned sw = (unsigned)((l15 & 7) << 4);
        fx4 acc0 = {0.f, 0.f, 0.f, 0.f}, acc1 = {0.f, 0.f, 0.f, 0.f};
        #pragma unroll
        for (int ks = 0; ks < 16; ks += 2) {
            bfx8 pa0 = *(const bfx8*)(pbase + (((unsigned)(kh * 1024 + ks * 64 + g * 16)) ^ sw));
            bfx8 vv0 = *(const bfx8*)(vrow + ks * 32 + g * 8);
            bfx8 pa1 = *(const bfx8*)(pbase + (((unsigned)(kh * 1024 + (ks + 1) * 64 + g * 16)) ^ sw));
            bfx8 vv1 = *(const bfx8*)(vrow + (ks + 1) * 32 + g * 8);
            acc0 = __builtin_amdgcn_mfma_f32_16x16x32_bf16(pa0, vv0, acc0, 0, 0, 0);
            acc1 = __builtin_amdgcn_mfma_f32_16x16x32_bf16(pa1, vv1, acc1, 0, 0, 0);
        }
        if (kh == 1) {
            float4 pv;
            pv.x = acc0[0] + acc1[0]; pv.y = acc0[1] + acc1[1];
            pv.z = acc0[2] + acc1[2]; pv.w = acc0[3] + acc1[3];
            *(float4*)&psumPV[(ws * 64 + lane) * 4] = pv;
        }
        __syncthreads();   // B7
        if (kh == 0) {
            const float4 other = *(const float4*)&psumPV[(ws * 64 + lane) * 4];
            float oth[4] = {other.x, other.y, other.z, other.w};
            #pragma unroll
            for (int r = 0; r < 4; r++) {
                int qrow = g * 4 + r;
                float denom = partsum[qrow * 8 + 0] + partsum[qrow * 8 + 1] +
                              partsum[qrow * 8 + 2] + partsum[qrow * 8 + 3] +
                              partsum[qrow * 8 + 4] + partsum[qrow * 8 + 5] +
                              partsum[qrow * 8 + 6] + partsum[qrow * 8 + 7];
                float v = (acc0[r] + acc1[r] + oth[r]) / denom;
                size_t orow = (size_t)dir * 8192 + (size_t)(bh >> 3) * 1024 + qb * 16 + qrow;
                inner[orow * 512 + (bh & 7) * 64 + ws * 16 + l15] = f2bf(v);
            }
        }
    }
}

// ==========================================================================
// Kernel 4: out = inner @ wout + bout   (plain bf16 MFMA)
// ==========================================================================
__global__ __launch_bounds__(256) void outproj_kernel(
    const short* __restrict__ inner, const float* __restrict__ wout,
    const float* __restrict__ bout, float* __restrict__ out)
{
    const int mb = blockIdx.x;   // 0..127
    const int nb = blockIdx.y;   // 0..3
    const int tid = threadIdx.x;
    const int lane = tid & 63;
    const int w = tid >> 6, wm = w >> 1, wn = w & 1;
    const int l15 = lane & 15, g8 = (lane >> 4) * 8;

    __shared__ short As[128][40];
    __shared__ short Bs[128][40];

    fx4 acc[4][4];
    const fx4 z4 = {0.f, 0.f, 0.f, 0.f};
    for (int i = 0; i < 4; i++) for (int j = 0; j < 4; j++) acc[i][j] = z4;

    const int arow = tid >> 1, ahalf = (tid & 1) * 16;
    const int bk = tid >> 3, bnseg = (tid & 7) * 16;

    for (int kb = 0; kb < 512; kb += 32) {
        __syncthreads();
        {
            const short* src = inner + (size_t)(mb * 128 + arow) * 512 + kb + ahalf;
            bfx8 v0 = *(const bfx8*)src, v1 = *(const bfx8*)(src + 8);
            *(bfx8*)&As[arow][ahalf] = v0;
            *(bfx8*)&As[arow][ahalf + 8] = v1;
        }
        {
            const float* src = wout + (size_t)(kb + bk) * 512 + nb * 128 + bnseg;
            #pragma unroll
            for (int q = 0; q < 4; q++) {
                float4 v = *(const float4*)(src + q * 4);
                float vv[4] = {v.x, v.y, v.z, v.w};
                #pragma unroll
                for (int c = 0; c < 4; c++) Bs[bnseg + q * 4 + c][bk] = f2bf(vv[c]);
            }
        }
        __syncthreads();
        bfx8 af[4], bf[4];
        #pragma unroll
        for (int mt = 0; mt < 4; mt++) af[mt] = *(bfx8*)&As[wm * 64 + mt * 16 + l15][g8];
        #pragma unroll
        for (int nt = 0; nt < 4; nt++) bf[nt] = *(bfx8*)&Bs[wn * 64 + nt * 16 + l15][g8];
        #pragma unroll
        for (int mt = 0; mt < 4; mt++)
            #pragma unroll
            for (int nt = 0; nt < 4; nt++)
                acc[mt][nt] = __builtin_amdgcn_mfma_f32_16x16x32_bf16(af[mt], bf[nt], acc[mt][nt], 0, 0, 0);
    }
    #pragma unroll
    for (int mt = 0; mt < 4; mt++)
        #pragma unroll
        for (int nt = 0; nt < 4; nt++)
            #pragma unroll
            for (int r = 0; r < 4; r++) {
                int row = mb * 128 + wm * 64 + mt * 16 + (lane >> 4) * 4 + r;
                int col = nb * 128 + wn * 64 + nt * 16 + l15;
                out[(size_t)row * 512 + col] = acc[mt][nt][r] + bout[col];
            }
}

// ==========================================================================
extern "C" void kernel_launch(void* const* d_in, const int* in_sizes, int n_in,
                              void* d_out, int out_size, void* d_ws, size_t ws_size,
                              hipStream_t stream)
{
    const float* x    = (const float*)d_in[0];
    const float* y    = (const float*)d_in[1];
    const float* wq   = (const float*)d_in[2];
    const float* wkv  = (const float*)d_in[3];
    const float* wout = (const float*)d_in[4];
    const float* bout = (const float*)d_in[5];
    float* out = (float*)d_out;

    char* ws = (char*)d_ws;
    size_t off = 0;
    auto alloc = [&](size_t bytes) -> void* {
        void* p = ws + off; off += (bytes + 255) & ~(size_t)255; return p;
    };
    const size_t QP = (size_t)8 * 8 * 1024 * 128 * 2;   // 16.78 MB
    const size_t VB = (size_t)8192 * 512 * 2;           // 8.39 MB
    short* QpX = (short*)alloc(QP);
    short* KpX = (short*)alloc(QP);
    short* QpY = (short*)alloc(QP);
    short* KpY = (short*)alloc(QP);
    short* VbX = (short*)alloc(VB);
    short* VbY = (short*)alloc(VB);
    short* VtX = (short*)alloc(VB);
    short* VtY = (short*)alloc(VB);
    short* inner = (short*)alloc((size_t)2 * 8192 * 512 * 2);
    if (off > ws_size) return;

    proj_kernel<<<dim3(64, 12, 2), 256, 0, stream>>>(x, y, wq, wkv, QpX, KpX, VbX, QpY, KpY, VbY);
    transv_kernel<<<dim3(16, 64, 2), 256, 0, stream>>>(VbX, VbY, VtX, VtY);
    (void)hipFuncSetAttribute((const void*)attn_kernel,
                              hipFuncAttributeMaxDynamicSharedMemorySize, ATTN_LDS);
    attn_kernel<<<dim3(64, 64, 2), 512, ATTN_LDS, stream>>>(QpX, KpX, VtX, QpY, KpY, VtY, inner);
    outproj_kernel<<<dim3(128, 4, 1), 256, 0, stream>>>(inner, wout, bout, out);
}